// Round 11
// baseline (928.345 us; speedup 1.0000x reference)
//
#include <hip/hip_runtime.h>

#define E_TOTAL 200000
#define OUTD 5
#define NT128 1563            // ceil(200000/128); last tile has 64 valid edges
#define WP_USHORTS 532480     // W0p (262144) + W1p (262144) + W2p (8192)
#define XBF_USHORTS 2560000   // 10000 * 256 bf16 copy of x

typedef __attribute__((ext_vector_type(4))) float f32x4;
typedef __attribute__((ext_vector_type(16))) float f32x16;
typedef __attribute__((ext_vector_type(8))) __bf16 bf16x8;

static __device__ __forceinline__ unsigned short f2bf(float f) {
  union { float f; unsigned u; } v; v.f = f;
  unsigned u = v.u;
  unsigned r = (u + 0x7FFFu + ((u >> 16) & 1u)) >> 16;   // RNE
  return (unsigned short)r;
}
static __device__ __forceinline__ unsigned short f2bf_cast(float f) {
  __bf16 h = (__bf16)f;                                   // HW cvt, RNE
  return __builtin_bit_cast(unsigned short, h);
}

// ---------------------------------------------------------------------------
// Pack W0,W1 [512x512] into 32x32x16-bf16 fragment order:
//   off = ((wtile*32 + ks)*64 + lane)*8 + j, value = W[k][n]
// W2 [512x5] padded N=16 into 16x16x32 fragment order.
// ws layout (ushort): [0,262144) W0p | [262144,524288) W1p | [524288,532480) W2p
//                     [532480, +2560000) xbf (if ws_size permits)
// ---------------------------------------------------------------------------
__global__ __launch_bounds__(256) void pack_weights(
    const float* __restrict__ W0, const float* __restrict__ W1,
    const float* __restrict__ W2, unsigned short* __restrict__ wp) {
  int tid = blockIdx.x * 256 + threadIdx.x;
  if (tid < 2 * 262144) {
    int sel = tid >> 18;
    int t = tid & 262143;
    int n = t & 511, k = t >> 9;            // coalesced read along n
    const float* W = sel ? W1 : W0;
    float val = W[k * 512 + n];
    int ntile = n >> 5, ks = k >> 4;
    int lane = (((k >> 3) & 1) << 5) | (n & 31);
    int j = k & 7;
    int off = (((ntile * 32 + ks) * 64 + lane) << 3) | j;
    wp[sel * 262144 + off] = f2bf(val);
  } else {
    int t2 = tid - 524288;
    if (t2 < 8192) {                         // W2 padded N=5 -> 16
      int j = t2 & 7, lane = (t2 >> 3) & 63, k0 = t2 >> 9;
      int k = k0 * 32 + ((lane >> 4) << 3) + j;
      int n = lane & 15;
      float val = (n < OUTD) ? W2[k * OUTD + n] : 0.0f;
      wp[524288 + t2] = f2bf(val);
    }
  }
}

// fp32 x -> bf16 copy (one-shot, memory-bound)
__global__ __launch_bounds__(256) void convert_x(
    const float* __restrict__ x, unsigned short* __restrict__ xbf) {
  int i = blockIdx.x * 256 + threadIdx.x;    // 8 elems each
  if (i < 320000) {
    const float4 f0 = *(const float4*)(x + (size_t)i * 8);
    const float4 f1 = *(const float4*)(x + (size_t)i * 8 + 4);
    uint4 pk;
    pk.x = (unsigned)f2bf(f0.x) | ((unsigned)f2bf(f0.y) << 16);
    pk.y = (unsigned)f2bf(f0.z) | ((unsigned)f2bf(f0.w) << 16);
    pk.z = (unsigned)f2bf(f1.x) | ((unsigned)f2bf(f1.y) << 16);
    pk.w = (unsigned)f2bf(f1.z) | ((unsigned)f2bf(f1.w) << 16);
    *(uint4*)(xbf + (size_t)i * 8) = pk;
  }
}

// ---------------------------------------------------------------------------
// Fused edge-MLP, operand-swapped, BIG-REGISTER 4-wave blocks:
// One block = 128 edges, 256 threads (4 waves), 1 block/CU, 1 wave/SIMD ->
// __launch_bounds__(256,1) = 512-reg unified budget per wave.
// Wave w owns features w*128..+127 (4 ft-tiles) x 128 edges (4 e-tiles):
// acc 16 x f32x16 = 256 AGPR; 12 bf16x8 weight regs (depth-2 prefetch,
// ~1024 cyc latency cover); 4 e-frags. Weight L2 traffic HALVES vs 64-edge
// tiles (4 loads feed 16 MFMAs = 512 pipe-cyc). L1 weight first-loads
// hoisted before L0 epilogue barrier; W2 before L1 epilogue.
// LDS: [128 rows][512 cols] bf16 A/H (131072 B, swizzle byte^=(row&7)<<4)
// + 2560 B obuf = 133632 B. Layer 2: wave w -> edges w*32..+31 (2 16-edge
// halves), pair-mean __shfl_xor(.,1); feature-4 written only by q==1.
// ---------------------------------------------------------------------------
template <int XBF>
__global__ __launch_bounds__(256, 1) void edge_mlp(
    const float* __restrict__ x, const unsigned short* __restrict__ xbf,
    const int* __restrict__ eidx,
    const float* __restrict__ b0, const float* __restrict__ b1,
    const float* __restrict__ b2, const unsigned short* __restrict__ wp,
    float* __restrict__ out) {
  __shared__ uint4 ldsv[8192 + 160];          // 131072 + 2560 B
  unsigned char* lds = (unsigned char*)ldsv;
  float* obuf = (float*)(lds + 131072);       // 128*5 f32

  const int tid = threadIdx.x;
  const int lane = tid & 63;
  const int w = tid >> 6;                     // wave 0..3
  const int l31 = lane & 31, h = lane >> 5;
  const int l15 = lane & 15, q = lane >> 4;
  const unsigned t = blockIdx.x;

  // ---- L0 weight bases + first two fragment loads (issued before staging)
  const unsigned short* wbA = wp + (size_t)(4 * w) * 16384 + (size_t)lane * 8;
  const unsigned short* wbB = wbA + 16384;
  const unsigned short* wbC = wbA + 32768;
  const unsigned short* wbD = wbA + 49152;
  bf16x8 cwA = *(const bf16x8*)wbA;
  bf16x8 cwB = *(const bf16x8*)wbB;
  bf16x8 cwC = *(const bf16x8*)wbC;
  bf16x8 cwD = *(const bf16x8*)wbD;
  bf16x8 nwA = *(const bf16x8*)(wbA + 512);
  bf16x8 nwB = *(const bf16x8*)(wbB + 512);
  bf16x8 nwC = *(const bf16x8*)(wbC + 512);
  bf16x8 nwD = *(const bf16x8*)(wbD + 512);

  // ---- stage gathered inputs: A[128][512] bf16, cols 0..255=x[src], 256..511=x[dst]
  {
    const int p = tid & 7;                    // 8 threads per row, 4 passes
#pragma unroll
    for (int pass = 0; pass < 4; ++pass) {
      const int r = (tid >> 3) + 32 * pass;
      int e = (int)t * 128 + r; if (e >= E_TOTAL) e = E_TOTAL - 1;
      const int node = eidx[(p >> 2) * E_TOTAL + e];
      const unsigned rowb = (unsigned)r * 1024;
      const unsigned sx = (unsigned)((r & 7) << 4);
      const unsigned cb0 = (unsigned)((p >> 2) * 512 + (p & 3) * 128);
      if (XBF) {
        const unsigned short* s = xbf + (size_t)node * 256 + (p & 3) * 64;
#pragma unroll
        for (int jj = 0; jj < 8; ++jj) {
          const int kk = (jj + p) & 7;        // phase by p: conflict-spread writes
          uint4 pk = *(const uint4*)(s + kk * 8);
          *(uint4*)(lds + rowb + ((cb0 + (unsigned)kk * 16) ^ sx)) = pk;
        }
      } else {
        const float* s = x + (size_t)node * 256 + (p & 3) * 64;
#pragma unroll
        for (int jj = 0; jj < 8; ++jj) {
          const int kk = (jj + p) & 7;
          const float4 f0 = *(const float4*)(s + kk * 8);
          const float4 f1 = *(const float4*)(s + kk * 8 + 4);
          uint4 pk;
          pk.x = (unsigned)f2bf(f0.x) | ((unsigned)f2bf(f0.y) << 16);
          pk.y = (unsigned)f2bf(f0.z) | ((unsigned)f2bf(f0.w) << 16);
          pk.z = (unsigned)f2bf(f1.x) | ((unsigned)f2bf(f1.y) << 16);
          pk.w = (unsigned)f2bf(f1.z) | ((unsigned)f2bf(f1.w) << 16);
          *(uint4*)(lds + rowb + ((cb0 + (unsigned)kk * 16) ^ sx)) = pk;
        }
      }
    }
  }
  __syncthreads();

  const unsigned sx31 = (unsigned)((l31 & 7) << 4);  // k-loop read & epi swizzle
  bf16x8 w2c0, w2c1, w2c2, w2c3;              // W2 prefetch (filled after L1 loop)
  const unsigned short* w2b = wp + 524288 + (size_t)lane * 8;

  // ===== hidden layers =====
#pragma unroll 1
  for (int L = 0; L < 2; ++L) {
    const float* bias = L ? b1 : b0;

    // bias C-init: reg 4*qd+rr -> feature w*128 + F*32 + 8*qd + 4*h + rr
    f32x16 aA0, aA1, aA2, aA3, aB0, aB1, aB2, aB3;
    f32x16 aC0, aC1, aC2, aC3, aD0, aD1, aD2, aD3;
#define BINIT(A0, A1, A2, A3, F)                                               \
    {                                                                          \
      _Pragma("unroll")                                                        \
      for (int qd = 0; qd < 4; ++qd) {                                         \
        const float4 bq = *(const float4*)(bias + w * 128 + (F) * 32 + 8 * qd + 4 * h); \
        _Pragma("unroll")                                                      \
        for (int rr = 0; rr < 4; ++rr) {                                       \
          (A0)[4 * qd + rr] = bq[rr]; (A1)[4 * qd + rr] = bq[rr];              \
          (A2)[4 * qd + rr] = bq[rr]; (A3)[4 * qd + rr] = bq[rr];              \
        }                                                                      \
      }                                                                        \
    }
    BINIT(aA0, aA1, aA2, aA3, 0) BINIT(aB0, aB1, aB2, aB3, 1)
    BINIT(aC0, aC1, aC2, aC3, 2) BINIT(aD0, aD1, aD2, aD3, 3)
#undef BINIT

#pragma unroll 2
    for (int ks = 0; ks < 32; ++ks) {
      const int kp = (ks + 2) & 31;           // depth-2 prefetch, branchless wrap
      bf16x8 tA = *(const bf16x8*)(wbA + kp * 512);
      bf16x8 tB = *(const bf16x8*)(wbB + kp * 512);
      bf16x8 tC = *(const bf16x8*)(wbC + kp * 512);
      bf16x8 tD = *(const bf16x8*)(wbD + kp * 512);
      const unsigned cb = (unsigned)(ks * 32 + h * 16);
      bf16x8 e0 = *(const bf16x8*)(lds + (unsigned)l31 * 1024 + (cb ^ sx31));
      bf16x8 e1 = *(const bf16x8*)(lds + (unsigned)(32 + l31) * 1024 + (cb ^ sx31));
      bf16x8 e2 = *(const bf16x8*)(lds + (unsigned)(64 + l31) * 1024 + (cb ^ sx31));
      bf16x8 e3 = *(const bf16x8*)(lds + (unsigned)(96 + l31) * 1024 + (cb ^ sx31));
      __builtin_amdgcn_s_setprio(1);
      aA0 = __builtin_amdgcn_mfma_f32_32x32x16_bf16(cwA, e0, aA0, 0, 0, 0);
      aB0 = __builtin_amdgcn_mfma_f32_32x32x16_bf16(cwB, e0, aB0, 0, 0, 0);
      aC0 = __builtin_amdgcn_mfma_f32_32x32x16_bf16(cwC, e0, aC0, 0, 0, 0);
      aD0 = __builtin_amdgcn_mfma_f32_32x32x16_bf16(cwD, e0, aD0, 0, 0, 0);
      aA1 = __builtin_amdgcn_mfma_f32_32x32x16_bf16(cwA, e1, aA1, 0, 0, 0);
      aB1 = __builtin_amdgcn_mfma_f32_32x32x16_bf16(cwB, e1, aB1, 0, 0, 0);
      aC1 = __builtin_amdgcn_mfma_f32_32x32x16_bf16(cwC, e1, aC1, 0, 0, 0);
      aD1 = __builtin_amdgcn_mfma_f32_32x32x16_bf16(cwD, e1, aD1, 0, 0, 0);
      aA2 = __builtin_amdgcn_mfma_f32_32x32x16_bf16(cwA, e2, aA2, 0, 0, 0);
      aB2 = __builtin_amdgcn_mfma_f32_32x32x16_bf16(cwB, e2, aB2, 0, 0, 0);
      aC2 = __builtin_amdgcn_mfma_f32_32x32x16_bf16(cwC, e2, aC2, 0, 0, 0);
      aD2 = __builtin_amdgcn_mfma_f32_32x32x16_bf16(cwD, e2, aD2, 0, 0, 0);
      aA3 = __builtin_amdgcn_mfma_f32_32x32x16_bf16(cwA, e3, aA3, 0, 0, 0);
      aB3 = __builtin_amdgcn_mfma_f32_32x32x16_bf16(cwB, e3, aB3, 0, 0, 0);
      aC3 = __builtin_amdgcn_mfma_f32_32x32x16_bf16(cwC, e3, aC3, 0, 0, 0);
      aD3 = __builtin_amdgcn_mfma_f32_32x32x16_bf16(cwD, e3, aD3, 0, 0, 0);
      __builtin_amdgcn_s_setprio(0);
      cwA = nwA; cwB = nwB; cwC = nwC; cwD = nwD;
      nwA = tA; nwB = tB; nwC = tC; nwD = tD;
    }

    // ---- hoist next phase's first weight loads BEFORE the epilogue barrier
    if (L == 0) {
      wbA = wp + 262144 + (size_t)(4 * w) * 16384 + (size_t)lane * 8;
      wbB = wbA + 16384; wbC = wbA + 32768; wbD = wbA + 49152;
      cwA = *(const bf16x8*)wbA;  cwB = *(const bf16x8*)wbB;
      cwC = *(const bf16x8*)wbC;  cwD = *(const bf16x8*)wbD;
      nwA = *(const bf16x8*)(wbA + 512); nwB = *(const bf16x8*)(wbB + 512);
      nwC = *(const bf16x8*)(wbC + 512); nwD = *(const bf16x8*)(wbD + 512);
    } else {
      w2c0 = *(const bf16x8*)w2b;
      w2c1 = *(const bf16x8*)(w2b + 512);
      w2c2 = *(const bf16x8*)(w2b + 1024);
      w2c3 = *(const bf16x8*)(w2b + 1536);
    }

    __syncthreads();   // all waves done reading A/H; only AGPR acc lives across

    // relu + cvt + write H over A, b64 quads.
    // C layout: col(lane&31)=edge, row(reg)=(reg&3)+8*(reg>>2)+4h = feature
    // quad byte col = 256w + 64*F + 16qd + 8h, XOR (edge&7)<<4.
#define EPI_TILE(ACC, F, ET)                                                   \
    {                                                                          \
      const unsigned rowb = (unsigned)((ET) * 32 + l31) * 1024;                \
      const unsigned cbase = (unsigned)(256 * w + 64 * (F) + 8 * h);           \
      _Pragma("unroll")                                                        \
      for (int qd = 0; qd < 4; ++qd) {                                         \
        uint2 pk2;                                                             \
        pk2.x = (unsigned)f2bf_cast(fmaxf((ACC)[4 * qd + 0], 0.f)) |           \
                ((unsigned)f2bf_cast(fmaxf((ACC)[4 * qd + 1], 0.f)) << 16);    \
        pk2.y = (unsigned)f2bf_cast(fmaxf((ACC)[4 * qd + 2], 0.f)) |           \
                ((unsigned)f2bf_cast(fmaxf((ACC)[4 * qd + 3], 0.f)) << 16);    \
        *(uint2*)(lds + rowb + ((cbase + 16u * qd) ^ sx31)) = pk2;             \
      }                                                                        \
    }
    EPI_TILE(aA0, 0, 0) EPI_TILE(aA1, 0, 1) EPI_TILE(aA2, 0, 2) EPI_TILE(aA3, 0, 3)
    EPI_TILE(aB0, 1, 0) EPI_TILE(aB1, 1, 1) EPI_TILE(aB2, 1, 2) EPI_TILE(aB3, 1, 3)
    EPI_TILE(aC0, 2, 0) EPI_TILE(aC1, 2, 1) EPI_TILE(aC2, 2, 2) EPI_TILE(aC3, 2, 3)
    EPI_TILE(aD0, 3, 0) EPI_TILE(aD1, 3, 1) EPI_TILE(aD2, 3, 2) EPI_TILE(aD3, 3, 3)
#undef EPI_TILE
    __syncthreads();
  }

  // ===== layer 2 (swapped): wave w -> edges w*32..w*32+31 in two 16-e halves
  {
#pragma unroll
    for (int g = 0; g < 2; ++g) {
      f32x4 acc2; acc2[0] = 0.f; acc2[1] = 0.f; acc2[2] = 0.f; acc2[3] = 0.f;
      const unsigned row = (unsigned)(w * 32 + g * 16 + l15);  // edge
      const unsigned rsx = (row & 7) << 4;
#pragma unroll
      for (int k0 = 0; k0 < 16; ++k0) {
        bf16x8 eF = *(const bf16x8*)(lds + row * 1024 + (((unsigned)(k0 * 64 + q * 16)) ^ rsx));
        bf16x8 wF = (k0 == 0) ? w2c0 : (k0 == 1) ? w2c1 : (k0 == 2) ? w2c2 :
                    (k0 == 3) ? w2c3 : *(const bf16x8*)(w2b + k0 * 512);
        acc2 = __builtin_amdgcn_mfma_f32_16x16x32_bf16(wF, eF, acc2, 0, 0, 0);
      }
      // C: col(l15)=edge, row(q*4+r)=feature. Pair-mean across edges (e, e^1).
      const int e = w * 32 + g * 16 + l15;
#pragma unroll
      for (int r = 0; r < 4; ++r) {
        const float s = __shfl_xor(acc2[r], 1);
        const float m = 0.5f * (acc2[r] + s);
        if (q == 0) {
          obuf[e * OUTD + r] = m + b2[r];
        } else if (q == 1 && r == 0) {        // feature 4 ONLY from q==1
          obuf[e * OUTD + 4] = m + b2[4];
        }
      }
    }
  }
  __syncthreads();

  // ===== coalesced out store (full 64B lines) =====
  {
    const int ve = (t == NT128 - 1) ? 64 : 128;
    const int nv4 = (ve * OUTD) >> 2;         // 160 or 80 uint4
    uint4* dst = (uint4*)(out + (size_t)t * 640);
    const uint4* sob = (const uint4*)obuf;
    if (tid < nv4) dst[tid] = sob[tid];
  }
}

extern "C" void kernel_launch(void* const* d_in, const int* in_sizes, int n_in,
                              void* d_out, int out_size, void* d_ws, size_t ws_size,
                              hipStream_t stream) {
  const float* x  = (const float*)d_in[0];
  const int* eidx = (const int*)d_in[1];
  const float* W0 = (const float*)d_in[2];
  const float* b0 = (const float*)d_in[3];
  const float* W1 = (const float*)d_in[4];
  const float* b1 = (const float*)d_in[5];
  const float* W2 = (const float*)d_in[6];
  const float* b2 = (const float*)d_in[7];
  float* out = (float*)d_out;
  unsigned short* wp = (unsigned short*)d_ws;
  if (ws_size < (size_t)WP_USHORTS * 2) return;   // ~1.04 MB minimum

  pack_weights<<<2080, 256, 0, stream>>>(W0, W1, W2, wp);
  if (ws_size >= (size_t)(WP_USHORTS + XBF_USHORTS) * 2) {
    unsigned short* xbf = wp + WP_USHORTS;
    convert_x<<<1250, 256, 0, stream>>>(x, xbf);
    edge_mlp<1><<<NT128, 256, 0, stream>>>(x, xbf, eidx, b0, b1, b2, wp, out);
  } else {
    edge_mlp<0><<<NT128, 256, 0, stream>>>(x, nullptr, eidx, b0, b1, b2, wp, out);
  }
}

// Round 12
// 265.516 us; speedup vs baseline: 3.4964x; 3.4964x over previous
//
#include <hip/hip_runtime.h>

#define E_TOTAL 200000
#define OUTD 5
#define NT128 1563            // ceil(200000/128); last tile: 64 valid edges
#define WP_USHORTS 532480     // W0p (262144) + W1p (262144) + W2p (8192)
#define XBF_USHORTS 2560000   // 10000 * 256 bf16 copy of x

typedef __attribute__((ext_vector_type(4))) float f32x4;
typedef __attribute__((ext_vector_type(16))) float f32x16;
typedef __attribute__((ext_vector_type(8))) __bf16 bf16x8;

static __device__ __forceinline__ unsigned short f2bf(float f) {
  union { float f; unsigned u; } v; v.f = f;
  unsigned u = v.u;
  unsigned r = (u + 0x7FFFu + ((u >> 16) & 1u)) >> 16;   // RNE
  return (unsigned short)r;
}
static __device__ __forceinline__ unsigned short f2bf_cast(float f) {
  __bf16 h = (__bf16)f;                                   // HW cvt, RNE
  return __builtin_bit_cast(unsigned short, h);
}

// ---------------------------------------------------------------------------
// Pack W0,W1 [512x512] into 32x32x16-bf16 fragment order:
//   off = ((wtile*32 + ks)*64 + lane)*8 + j, value = W[k][n]
// W2 [512x5] padded N=16 into 16x16x32 fragment order.
// ws layout (ushort): [0,262144) W0p | [262144,524288) W1p | [524288,532480) W2p
//                     [532480, +2560000) xbf (if ws_size permits)
// ---------------------------------------------------------------------------
__global__ __launch_bounds__(256) void pack_weights(
    const float* __restrict__ W0, const float* __restrict__ W1,
    const float* __restrict__ W2, unsigned short* __restrict__ wp) {
  int tid = blockIdx.x * 256 + threadIdx.x;
  if (tid < 2 * 262144) {
    int sel = tid >> 18;
    int t = tid & 262143;
    int n = t & 511, k = t >> 9;            // coalesced read along n
    const float* W = sel ? W1 : W0;
    float val = W[k * 512 + n];
    int ntile = n >> 5, ks = k >> 4;
    int lane = (((k >> 3) & 1) << 5) | (n & 31);
    int j = k & 7;
    int off = (((ntile * 32 + ks) * 64 + lane) << 3) | j;
    wp[sel * 262144 + off] = f2bf(val);
  } else {
    int t2 = tid - 524288;
    if (t2 < 8192) {                         // W2 padded N=5 -> 16
      int j = t2 & 7, lane = (t2 >> 3) & 63, k0 = t2 >> 9;
      int k = k0 * 32 + ((lane >> 4) << 3) + j;
      int n = lane & 15;
      float val = (n < OUTD) ? W2[k * OUTD + n] : 0.0f;
      wp[524288 + t2] = f2bf(val);
    }
  }
}

// fp32 x -> bf16 copy (one-shot, memory-bound)
__global__ __launch_bounds__(256) void convert_x(
    const float* __restrict__ x, unsigned short* __restrict__ xbf) {
  int i = blockIdx.x * 256 + threadIdx.x;    // 8 elems each
  if (i < 320000) {
    const float4 f0 = *(const float4*)(x + (size_t)i * 8);
    const float4 f1 = *(const float4*)(x + (size_t)i * 8 + 4);
    uint4 pk;
    pk.x = (unsigned)f2bf(f0.x) | ((unsigned)f2bf(f0.y) << 16);
    pk.y = (unsigned)f2bf(f0.z) | ((unsigned)f2bf(f0.w) << 16);
    pk.z = (unsigned)f2bf(f1.x) | ((unsigned)f2bf(f1.y) << 16);
    pk.w = (unsigned)f2bf(f1.z) | ((unsigned)f2bf(f1.w) << 16);
    *(uint4*)(xbf + (size_t)i * 8) = pk;
  }
}

// ---------------------------------------------------------------------------
// Fused edge-MLP, operand-swapped, 128-EDGE tiles, 8 waves (512 thr),
// 1 block/CU (2 waves/SIMD, 256-reg budget). Halves the per-edge weight
// stream vs 64-edge tiles (1 MB / 128 edges): same R9 per-wave shape --
// wave (fg=w>>1, eg=w&1) owns features fg*128..+127 (4 ft-tiles) x edges
// eg*64..+63 (2 e-tiles): acc 8 x f32x16 (128 AGPR), 4 weight loads +
// 2 ds_read_b128 + 8 MFMA per k-step, depth-1 prefetch, bias C-init,
// L1 first-loads hoisted before L0's epilogue barrier (no extra regs).
// LDS: [128 rows][512 cols] bf16 A/H (131072 B, swizzle byte^=(row&7)<<4)
// + 2560 B obuf. Layer 2: wave w -> edges w*16..+15, pair-mean
// __shfl_xor(.,1); feature-4 written only by q==1.
// ---------------------------------------------------------------------------
template <int XBF>
__global__ __launch_bounds__(512, 2) void edge_mlp(
    const float* __restrict__ x, const unsigned short* __restrict__ xbf,
    const int* __restrict__ eidx,
    const float* __restrict__ b0, const float* __restrict__ b1,
    const float* __restrict__ b2, const unsigned short* __restrict__ wp,
    float* __restrict__ out) {
  __shared__ uint4 ldsv[8192 + 160];          // 131072 + 2560 B
  unsigned char* lds = (unsigned char*)ldsv;
  float* obuf = (float*)(lds + 131072);       // 128*5 f32

  const int tid = threadIdx.x;
  const int lane = tid & 63;
  const int w = tid >> 6;                     // wave 0..7
  const int fg = w >> 1;                      // feature group 0..3
  const int eg = w & 1;                       // edge group 0..1
  const int l31 = lane & 31, h = lane >> 5;
  const int l15 = lane & 15, q = lane >> 4;
  const unsigned t = blockIdx.x;

  // ---- L0 weight bases + first fragment loads (issued before staging) ----
  const unsigned short* wbA = wp + (size_t)(4 * fg) * 16384 + (size_t)lane * 8;
  const unsigned short* wbB = wbA + 16384;
  const unsigned short* wbC = wbA + 32768;
  const unsigned short* wbD = wbA + 49152;
  bf16x8 cwA = *(const bf16x8*)wbA;
  bf16x8 cwB = *(const bf16x8*)wbB;
  bf16x8 cwC = *(const bf16x8*)wbC;
  bf16x8 cwD = *(const bf16x8*)wbD;

  // ---- stage gathered inputs: A[128][512] bf16, cols 0..255=x[src], 256..511=x[dst]
  {
    const int p = tid & 7;                    // 8 threads per row, 2 passes
#pragma unroll
    for (int pass = 0; pass < 2; ++pass) {
      const int r = (tid >> 3) + 64 * pass;
      int e = (int)t * 128 + r; if (e >= E_TOTAL) e = E_TOTAL - 1;
      const int node = eidx[(p >> 2) * E_TOTAL + e];
      const unsigned rowb = (unsigned)r * 1024;
      const unsigned sx = (unsigned)((r & 7) << 4);
      const unsigned cb0 = (unsigned)((p >> 2) * 512 + (p & 3) * 128);
      if (XBF) {
        const unsigned short* s = xbf + (size_t)node * 256 + (p & 3) * 64;
#pragma unroll
        for (int jj = 0; jj < 8; ++jj) {
          const int kk = (jj + p) & 7;        // phase by p: conflict-spread writes
          uint4 pk = *(const uint4*)(s + kk * 8);
          *(uint4*)(lds + rowb + ((cb0 + (unsigned)kk * 16) ^ sx)) = pk;
        }
      } else {
        const float* s = x + (size_t)node * 256 + (p & 3) * 64;
#pragma unroll
        for (int jj = 0; jj < 8; ++jj) {
          const int kk = (jj + p) & 7;
          const float4 f0 = *(const float4*)(s + kk * 8);
          const float4 f1 = *(const float4*)(s + kk * 8 + 4);
          uint4 pk;
          pk.x = (unsigned)f2bf(f0.x) | ((unsigned)f2bf(f0.y) << 16);
          pk.y = (unsigned)f2bf(f0.z) | ((unsigned)f2bf(f0.w) << 16);
          pk.z = (unsigned)f2bf(f1.x) | ((unsigned)f2bf(f1.y) << 16);
          pk.w = (unsigned)f2bf(f1.z) | ((unsigned)f2bf(f1.w) << 16);
          *(uint4*)(lds + rowb + ((cb0 + (unsigned)kk * 16) ^ sx)) = pk;
        }
      }
    }
  }
  __syncthreads();

  const unsigned sx31 = (unsigned)((l31 & 7) << 4);  // k-loop read & epi swizzle
  const unsigned short* w2b = wp + 524288 + (size_t)lane * 8;
  const unsigned erow0 = (unsigned)(eg * 64 + l31);  // e-tile rows
  const unsigned erow1 = erow0 + 32;

  // ===== hidden layers =====
#pragma unroll 1
  for (int L = 0; L < 2; ++L) {
    const float* bias = L ? b1 : b0;

    // bias C-init: reg 4*qd+rr -> feature fg*128 + F*32 + 8*qd + 4*h + rr
    f32x16 aA0, aA1, aB0, aB1, aC0, aC1, aD0, aD1;
#define BINIT(ACC0, ACC1, F)                                                   \
    {                                                                          \
      _Pragma("unroll")                                                        \
      for (int qd = 0; qd < 4; ++qd) {                                         \
        const float4 bq = *(const float4*)(bias + fg * 128 + (F) * 32 + 8 * qd + 4 * h); \
        _Pragma("unroll")                                                      \
        for (int rr = 0; rr < 4; ++rr) {                                       \
          (ACC0)[4 * qd + rr] = bq[rr];                                        \
          (ACC1)[4 * qd + rr] = bq[rr];                                        \
        }                                                                      \
      }                                                                        \
    }
    BINIT(aA0, aA1, 0) BINIT(aB0, aB1, 1) BINIT(aC0, aC1, 2) BINIT(aD0, aD1, 3)
#undef BINIT

#pragma unroll 2
    for (int ks = 0; ks < 32; ++ks) {
      const int kp = (ks + 1) & 31;           // depth-1 prefetch, branchless wrap
      bf16x8 nwA = *(const bf16x8*)(wbA + kp * 512);
      bf16x8 nwB = *(const bf16x8*)(wbB + kp * 512);
      bf16x8 nwC = *(const bf16x8*)(wbC + kp * 512);
      bf16x8 nwD = *(const bf16x8*)(wbD + kp * 512);
      const unsigned cb = (unsigned)(ks * 32 + h * 16);
      bf16x8 e0 = *(const bf16x8*)(lds + erow0 * 1024 + (cb ^ sx31));
      bf16x8 e1 = *(const bf16x8*)(lds + erow1 * 1024 + (cb ^ sx31));
      __builtin_amdgcn_s_setprio(1);
      aA0 = __builtin_amdgcn_mfma_f32_32x32x16_bf16(cwA, e0, aA0, 0, 0, 0);
      aB0 = __builtin_amdgcn_mfma_f32_32x32x16_bf16(cwB, e0, aB0, 0, 0, 0);
      aC0 = __builtin_amdgcn_mfma_f32_32x32x16_bf16(cwC, e0, aC0, 0, 0, 0);
      aD0 = __builtin_amdgcn_mfma_f32_32x32x16_bf16(cwD, e0, aD0, 0, 0, 0);
      aA1 = __builtin_amdgcn_mfma_f32_32x32x16_bf16(cwA, e1, aA1, 0, 0, 0);
      aB1 = __builtin_amdgcn_mfma_f32_32x32x16_bf16(cwB, e1, aB1, 0, 0, 0);
      aC1 = __builtin_amdgcn_mfma_f32_32x32x16_bf16(cwC, e1, aC1, 0, 0, 0);
      aD1 = __builtin_amdgcn_mfma_f32_32x32x16_bf16(cwD, e1, aD1, 0, 0, 0);
      __builtin_amdgcn_s_setprio(0);
      cwA = nwA; cwB = nwB; cwC = nwC; cwD = nwD;
    }

    // ---- hoist next layer's first weight loads BEFORE the epilogue barrier
    if (L == 0) {
      wbA = wp + 262144 + (size_t)(4 * fg) * 16384 + (size_t)lane * 8;
      wbB = wbA + 16384; wbC = wbA + 32768; wbD = wbA + 49152;
      cwA = *(const bf16x8*)wbA;  cwB = *(const bf16x8*)wbB;
      cwC = *(const bf16x8*)wbC;  cwD = *(const bf16x8*)wbD;
    }

    __syncthreads();   // all waves done reading A/H; only AGPR acc lives across

    // relu + cvt + write H over A, b64 quads.
    // C layout: col(lane&31)=edge, row(reg)=(reg&3)+8*(reg>>2)+4h = feature
    // quad byte col = 256*fg + 64*F + 16qd + 8h, XOR (edge&7)<<4.
#define EPI_TILE(ACC, F, ET)                                                   \
    {                                                                          \
      const unsigned rowb = (unsigned)(eg * 64 + (ET) * 32 + l31) * 1024;      \
      const unsigned cbase = (unsigned)(256 * fg + 64 * (F) + 8 * h);          \
      _Pragma("unroll")                                                        \
      for (int qd = 0; qd < 4; ++qd) {                                         \
        uint2 pk2;                                                             \
        pk2.x = (unsigned)f2bf_cast(fmaxf((ACC)[4 * qd + 0], 0.f)) |           \
                ((unsigned)f2bf_cast(fmaxf((ACC)[4 * qd + 1], 0.f)) << 16);    \
        pk2.y = (unsigned)f2bf_cast(fmaxf((ACC)[4 * qd + 2], 0.f)) |           \
                ((unsigned)f2bf_cast(fmaxf((ACC)[4 * qd + 3], 0.f)) << 16);    \
        *(uint2*)(lds + rowb + ((cbase + 16u * qd) ^ sx31)) = pk2;             \
      }                                                                        \
    }
    EPI_TILE(aA0, 0, 0) EPI_TILE(aA1, 0, 1)
    EPI_TILE(aB0, 1, 0) EPI_TILE(aB1, 1, 1)
    EPI_TILE(aC0, 2, 0) EPI_TILE(aC1, 2, 1)
    EPI_TILE(aD0, 3, 0) EPI_TILE(aD1, 3, 1)
#undef EPI_TILE
    __syncthreads();
  }

  // ===== layer 2 (swapped): wave w -> edges w*16..w*16+15, N=16 padded =====
  {
    f32x4 acc2; acc2[0] = 0.f; acc2[1] = 0.f; acc2[2] = 0.f; acc2[3] = 0.f;
    const unsigned row = (unsigned)(w * 16 + l15);     // edge (B-operand col)
    const unsigned rsx = (row & 7) << 4;
#pragma unroll
    for (int k0 = 0; k0 < 16; ++k0) {
      bf16x8 eF = *(const bf16x8*)(lds + row * 1024 + (((unsigned)(k0 * 64 + q * 16)) ^ rsx));
      bf16x8 wF = *(const bf16x8*)(w2b + k0 * 512);
      acc2 = __builtin_amdgcn_mfma_f32_16x16x32_bf16(wF, eF, acc2, 0, 0, 0);
    }
    // C: col(l15)=edge, row(q*4+r)=feature. Pair-mean across edges (e, e^1).
    const int e = w * 16 + l15;
#pragma unroll
    for (int r = 0; r < 4; ++r) {
      const float s = __shfl_xor(acc2[r], 1);
      const float m = 0.5f * (acc2[r] + s);
      if (q == 0) {
        obuf[e * OUTD + r] = m + b2[r];
      } else if (q == 1 && r == 0) {          // feature 4 ONLY from q==1
        obuf[e * OUTD + 4] = m + b2[4];
      }
    }
  }
  __syncthreads();

  // ===== coalesced out store (full 64B lines) =====
  {
    const int ve = (t == NT128 - 1) ? 64 : 128;
    const int nv4 = (ve * OUTD) >> 2;         // 160 or 80 uint4
    uint4* dst = (uint4*)(out + (size_t)t * 640);
    const uint4* sob = (const uint4*)obuf;
    if (tid < nv4) dst[tid] = sob[tid];
  }
}

extern "C" void kernel_launch(void* const* d_in, const int* in_sizes, int n_in,
                              void* d_out, int out_size, void* d_ws, size_t ws_size,
                              hipStream_t stream) {
  const float* x  = (const float*)d_in[0];
  const int* eidx = (const int*)d_in[1];
  const float* W0 = (const float*)d_in[2];
  const float* b0 = (const float*)d_in[3];
  const float* W1 = (const float*)d_in[4];
  const float* b1 = (const float*)d_in[5];
  const float* W2 = (const float*)d_in[6];
  const float* b2 = (const float*)d_in[7];
  float* out = (float*)d_out;
  unsigned short* wp = (unsigned short*)d_ws;
  if (ws_size < (size_t)WP_USHORTS * 2) return;   // ~1.04 MB minimum

  pack_weights<<<2080, 256, 0, stream>>>(W0, W1, W2, wp);
  if (ws_size >= (size_t)(WP_USHORTS + XBF_USHORTS) * 2) {
    unsigned short* xbf = wp + WP_USHORTS;
    convert_x<<<1250, 256, 0, stream>>>(x, xbf);
    edge_mlp<1><<<NT128, 512, 0, stream>>>(x, xbf, eidx, b0, b1, b2, wp, out);
  } else {
    edge_mlp<0><<<NT128, 512, 0, stream>>>(x, nullptr, eidx, b0, b1, b2, wp, out);
  }
}